// Round 1
// baseline (187.126 us; speedup 1.0000x reference)
//
#include <hip/hip_runtime.h>
#include <hip/hip_bf16.h>

typedef __attribute__((ext_vector_type(4))) float f32x4;
typedef __attribute__((ext_vector_type(8))) short s16x8;
typedef __attribute__((ext_vector_type(4))) short s16x4;

constexpr int S    = 2048;
constexpr int D    = 64;
constexpr int BH   = 32;   // B*H
constexpr int QBLK = 64;   // q rows per block (4 waves x 16)
constexpr int KBLK = 32;   // keys per iteration

__device__ __forceinline__ short f2bf(float f) {
  union { float f; unsigned u; } x;
  x.f = f;
  unsigned r = x.u + 0x7fffu + ((x.u >> 16) & 1u);  // RNE
  return (short)(r >> 16);
}

__global__ __launch_bounds__(256, 4)
void attn_fwd(const float* __restrict__ Qg, const float* __restrict__ Kg,
              const float* __restrict__ Vg, const float* __restrict__ Mg,
              float* __restrict__ Og) {
  // K tile bf16, padded to break stride-128B bank conflicts on ds_read_b128
  __shared__ alignas(16) short K_lds[KBLK][72];
  // V^T tile bf16: [d][key], padded
  __shared__ alignas(16) short V_lds[D][40];
  // wave-private masked-P stash: [wave][q][key], padded (stride 80B)
  __shared__ alignas(16) short P_lds[4][16][40];

  const int tid  = threadIdx.x;
  const int wave = tid >> 6;
  const int lane = tid & 63;
  const int lq   = lane & 15;  // q (and key-row / d-row) within 16-tile
  const int g    = lane >> 4;  // k-group

  const int bh = blockIdx.x & (BH - 1);
  const int qt = blockIdx.x / BH;

  const size_t base = (size_t)bh * S * D;
  const int    qrow = qt * QBLK + wave * 16 + lq;
  const float* mrow = Mg + ((size_t)bh * S + qrow) * S;

  // Q fragment (B operand of swapped QK^T), pre-scaled by log2(e)/8 (exact pow2 on bf16 path is folded pre-round)
  s16x8 qf[2];
  {
    const float sc = 1.44269504088896340736f * 0.125f;
    const float* qp = Qg + base + (size_t)qrow * D + g * 8;
    #pragma unroll
    for (int h = 0; h < 2; ++h) {
      f32x4 a = *(const f32x4*)(qp + h * 32);
      f32x4 b = *(const f32x4*)(qp + h * 32 + 4);
      #pragma unroll
      for (int j = 0; j < 4; ++j) {
        qf[h][j]     = f2bf(a[j] * sc);
        qf[h][4 + j] = f2bf(b[j] * sc);
      }
    }
  }

  f32x4 acc[4];
  #pragma unroll
  for (int dt = 0; dt < 4; ++dt) acc[dt] = (f32x4)0.0f;
  float m = -1e30f, l = 0.0f;

  for (int kb = 0; kb < S; kb += KBLK) {
    // mask tile for this lane's q-row (independent of LDS; issue early)
    f32x4 mk[2];
    #pragma unroll
    for (int t = 0; t < 2; ++t)
      mk[t] = *(const f32x4*)(mrow + kb + t * 16 + g * 4);

    __syncthreads();  // previous iteration's LDS reads done

    // ---- stage K tile (KBLK x 64 fp32 -> bf16) ----
    {
      const int row = tid >> 3;
      const int d0  = (tid & 7) * 8;
      const float* kp = Kg + base + (size_t)(kb + row) * D + d0;
      f32x4 a = *(const f32x4*)kp;
      f32x4 b = *(const f32x4*)(kp + 4);
      s16x8 f;
      #pragma unroll
      for (int j = 0; j < 4; ++j) { f[j] = f2bf(a[j]); f[4 + j] = f2bf(b[j]); }
      *(s16x8*)&K_lds[row][d0] = f;
    }
    // ---- stage V^T tile (strided global reads = coalesced 256B rows) ----
    {
      const int d  = tid & 63;
      const int kk = (tid >> 6) * 8;
      const float* vp = Vg + base + (size_t)(kb + kk) * D + d;
      s16x8 f;
      #pragma unroll
      for (int j = 0; j < 8; ++j) f[j] = f2bf(vp[(size_t)j * D]);
      *(s16x8*)&V_lds[d][kk] = f;
    }
    __syncthreads();

    // ---- swapped QK^T: st[t] = K_tile_t . Q^T  (C/D: col=q=lane&15, row=key=4g+r) ----
    f32x4 st[2];
    #pragma unroll
    for (int t = 0; t < 2; ++t) {
      st[t] = (f32x4)0.0f;
      #pragma unroll
      for (int h = 0; h < 2; ++h) {
        s16x8 kf = *(const s16x8*)&K_lds[t * 16 + lq][h * 32 + g * 8];
        st[t] = __builtin_amdgcn_mfma_f32_16x16x32_bf16(kf, qf[h], st[t], 0, 0, 0);
      }
    }

    // ---- online softmax in exp2 domain, per q = lane&15 ----
    float mx = st[0][0];
    #pragma unroll
    for (int t = 0; t < 2; ++t)
      #pragma unroll
      for (int r = 0; r < 4; ++r) mx = fmaxf(mx, st[t][r]);
    mx = fmaxf(mx, __shfl_xor(mx, 16));
    mx = fmaxf(mx, __shfl_xor(mx, 32));
    const float mn  = fmaxf(m, mx);
    const float fac = __builtin_amdgcn_exp2f(m - mn);
    float p[8], ps = 0.0f;
    #pragma unroll
    for (int t = 0; t < 2; ++t)
      #pragma unroll
      for (int r = 0; r < 4; ++r) {
        float e = __builtin_amdgcn_exp2f(st[t][r] - mn);
        p[t * 4 + r] = e;
        ps += e;
      }
    ps += __shfl_xor(ps, 16);
    ps += __shfl_xor(ps, 32);
    l = l * fac + ps;      // denominator WITHOUT dropout mask (reference masks post-softmax)
    m = mn;
    #pragma unroll
    for (int dt = 0; dt < 4; ++dt)
      #pragma unroll
      for (int r = 0; r < 4; ++r) acc[dt][r] *= fac;

    // ---- apply dropout mask, pack bf16, stash P in wave-private LDS ----
    #pragma unroll
    for (int t = 0; t < 2; ++t) {
      s16x4 pk;
      #pragma unroll
      for (int r = 0; r < 4; ++r) pk[r] = f2bf(p[t * 4 + r] * mk[t][r]);
      *(s16x4*)&P_lds[wave][lq][t * 16 + g * 4] = pk;  // key = 16t+4g+r
    }
    asm volatile("" ::: "memory");  // keep compiler from sinking the read above the writes

    // ---- swapped PV: acc[dt] += V^T_tile_dt . P^T  (C/D: col=q=lane&15, row=d=4g+r) ----
    s16x8 pf = *(const s16x8*)&P_lds[wave][lq][g * 8];
    #pragma unroll
    for (int dt = 0; dt < 4; ++dt) {
      s16x8 vf = *(const s16x8*)&V_lds[dt * 16 + lq][g * 8];
      acc[dt] = __builtin_amdgcn_mfma_f32_16x16x32_bf16(vf, pf, acc[dt], 0, 0, 0);
    }
  }

  const float inv_l = 1.0f / l;
  float* op = Og + base + (size_t)qrow * D;
  #pragma unroll
  for (int dt = 0; dt < 4; ++dt) {
    f32x4 o;
    #pragma unroll
    for (int r = 0; r < 4; ++r) o[r] = acc[dt][r] * inv_l;
    *(f32x4*)(op + dt * 16 + g * 4) = o;  // d = dt*16 + 4g + r
  }
}

extern "C" void kernel_launch(void* const* d_in, const int* in_sizes, int n_in,
                              void* d_out, int out_size, void* d_ws, size_t ws_size,
                              hipStream_t stream) {
  const float* Q = (const float*)d_in[0];
  const float* K = (const float*)d_in[1];
  const float* V = (const float*)d_in[2];
  const float* M = (const float*)d_in[3];
  float* O = (float*)d_out;
  dim3 grid((S / QBLK) * BH);  // 32 q-tiles * 32 heads = 1024 blocks
  attn_fwd<<<grid, 256, 0, stream>>>(Q, K, V, M, O);
}

// Round 2
// 182.462 us; speedup vs baseline: 1.0256x; 1.0256x over previous
//
#include <hip/hip_runtime.h>
#include <hip/hip_bf16.h>

typedef __attribute__((ext_vector_type(4))) float f32x4;
typedef __attribute__((ext_vector_type(8))) short s16x8;
typedef __attribute__((ext_vector_type(4))) short s16x4;

constexpr int S    = 2048;
constexpr int D    = 64;
constexpr int BH   = 32;   // B*H
constexpr int QBLK = 64;   // q rows per block (4 waves x 16)
constexpr int KBLK = 64;   // keys per main-loop iteration
constexpr int NSL  = S / KBLK;  // 32 slices

__device__ __forceinline__ short f2bf(float f) {
  union { float f; unsigned u; } x;
  x.f = f;
  unsigned r = x.u + 0x7fffu + ((x.u >> 16) & 1u);  // RNE
  return (short)(r >> 16);
}

typedef const __attribute__((address_space(1))) unsigned int* as1_u32p;
typedef __attribute__((address_space(3))) unsigned int* as3_u32p;

// ============ pre-pass: K -> bf16 (chunk-swizzled), V -> bf16 transposed (chunk-swizzled) ============
// Kb layout: [bh][key][pos][8] bf16 where pos = chunk ^ (key&7), chunk = d/8. Tile (64 keys) = 8KB contiguous.
// Vt layout: [bh][slice][d][pos][8] bf16 where pos = chunk ^ (d&7), chunk = (key%64)/8. Tile = 8KB contiguous.
__global__ __launch_bounds__(256) void prepass(const float* __restrict__ K,
                                               const float* __restrict__ V,
                                               short* __restrict__ Kb,
                                               short* __restrict__ Vt) {
  const int bid = blockIdx.x;
  const int tid = threadIdx.x;
  if (bid < BH * NSL) {
    // ---- K convert: one block per (bh, 64-key slice) ----
    const int bh = bid >> 5, sl = bid & 31;
    const float* src = K + ((size_t)bh * S + (size_t)sl * KBLK) * D;
    short* dst = Kb + ((size_t)bh * S + (size_t)sl * KBLK) * D;
    #pragma unroll
    for (int c = 0; c < 2; ++c) {
      const int idx = tid * 2 + c;       // chunk id within tile, 0..511
      const int row = idx >> 3;          // key within slice (key&7 == row&7)
      const int ch  = idx & 7;           // d-chunk
      const float* s = src + row * D + ch * 8;
      f32x4 a = *(const f32x4*)s, b = *(const f32x4*)(s + 4);
      s16x8 o;
      #pragma unroll
      for (int j = 0; j < 4; ++j) { o[j] = f2bf(a[j]); o[4 + j] = f2bf(b[j]); }
      *(s16x8*)(dst + row * D + ((ch ^ (row & 7)) * 8)) = o;
    }
  } else {
    // ---- V transpose: one block per (bh, 64-key slice) ----
    __shared__ short tile[64][72];       // [key][d], padded
    const int b2 = bid - BH * NSL;
    const int bh = b2 >> 5, sl = b2 & 31;
    const float* src = V + ((size_t)bh * S + (size_t)sl * KBLK) * D;
    {
      const int row = tid >> 2;          // key 0..63
      const int c0  = (tid & 3) * 16;    // d cols, 16 per thread
      #pragma unroll
      for (int q = 0; q < 4; ++q) {
        f32x4 a = *(const f32x4*)(src + row * D + c0 + q * 4);
        #pragma unroll
        for (int j = 0; j < 4; ++j) tile[row][c0 + q * 4 + j] = f2bf(a[j]);
      }
    }
    __syncthreads();
    short* dst = Vt + ((size_t)bh * NSL + sl) * (D * KBLK);
    #pragma unroll
    for (int c = 0; c < 2; ++c) {
      const int idx = tid * 2 + c;       // 0..511
      const int d  = idx >> 3;
      const int ch = idx & 7;            // key-chunk
      s16x8 o;
      #pragma unroll
      for (int j = 0; j < 8; ++j) o[j] = tile[ch * 8 + j][d];
      *(s16x8*)(dst + d * KBLK + ((ch ^ (d & 7)) * 8)) = o;
    }
  }
}

// ============ main: flash attention, double-buffered LDS, 1 barrier/iter ============
__global__ __launch_bounds__(256, 4)
void attn_fwd2(const float* __restrict__ Qg, const short* __restrict__ Kb,
               const short* __restrict__ Vt, const float* __restrict__ Mg,
               float* __restrict__ Og) {
  __shared__ short K_lds[2][KBLK][64];   // [buf][key][d-chunks swizzled], 128B rows
  __shared__ short V_lds[2][D][KBLK];    // [buf][d][key-chunks swizzled]
  __shared__ short P_lds[4][16][KBLK];   // wave-private, swizzled

  const int tid  = threadIdx.x;
  const int wave = tid >> 6;
  const int lane = tid & 63;
  const int lq   = lane & 15;
  const int g    = lane >> 4;

  const int bh = blockIdx.x & (BH - 1);
  const int qt = blockIdx.x / BH;
  const size_t base = (size_t)bh * S * D;
  const int    qrow = qt * QBLK + wave * 16 + lq;
  const float* mrow = Mg + ((size_t)bh * S + qrow) * S;

  // Q fragment, pre-scaled by log2(e)/8
  s16x8 qf[2];
  {
    const float sc = 1.44269504088896340736f * 0.125f;
    const float* qp = Qg + base + (size_t)qrow * D + g * 8;
    #pragma unroll
    for (int h = 0; h < 2; ++h) {
      f32x4 a = *(const f32x4*)(qp + h * 32);
      f32x4 b = *(const f32x4*)(qp + h * 32 + 4);
      #pragma unroll
      for (int j = 0; j < 4; ++j) {
        qf[h][j]     = f2bf(a[j] * sc);
        qf[h][4 + j] = f2bf(b[j] * sc);
      }
    }
  }

  f32x4 acc[4];
  #pragma unroll
  for (int dt = 0; dt < 4; ++dt) acc[dt] = (f32x4)0.0f;
  float m = -1e30f, l = 0.0f;

  const char* kbase = (const char*)(Kb + base);
  const char* vbase = (const char*)(Vt + (size_t)bh * NSL * D * KBLK);
  char* kl = (char*)&K_lds[0][0][0];
  char* vl = (char*)&V_lds[0][0][0];
  char* pl = (char*)&P_lds[wave][lq][0];

  auto stage = [&](int buf, int it) {
    const char* ks = kbase + (size_t)it * 8192;
    const char* vs = vbase + (size_t)it * 8192;
    #pragma unroll
    for (int c = 0; c < 2; ++c) {
      const int o = (wave * 2 + c) * 1024;
      __builtin_amdgcn_global_load_lds((as1_u32p)(ks + o + lane * 16),
                                       (as3_u32p)(kl + buf * 8192 + o), 16, 0, 0);
      __builtin_amdgcn_global_load_lds((as1_u32p)(vs + o + lane * 16),
                                       (as3_u32p)(vl + buf * 8192 + o), 16, 0, 0);
    }
  };

  stage(0, 0);
  __syncthreads();

  int cur = 0;
  for (int it = 0; it < NSL; ++it) {
    // prefetch next tile via async DMA (drained by next barrier, hidden under compute)
    if (it + 1 < NSL) stage(cur ^ 1, it + 1);

    // mask for this lane's q-row (consumed after softmax — in-iter slack + TLP hides latency)
    f32x4 mk[4];
    const float* mp = mrow + it * KBLK;
    #pragma unroll
    for (int t = 0; t < 4; ++t) mk[t] = *(const f32x4*)(mp + t * 16 + g * 4);

    // ---- swapped QK^T: st[t] rows = keys, cols = q ----
    f32x4 st[4];
    #pragma unroll
    for (int t = 0; t < 4; ++t) {
      st[t] = (f32x4)0.0f;
      #pragma unroll
      for (int h = 0; h < 2; ++h) {
        const s16x8 kf = *(const s16x8*)(kl + cur * 8192 + (t * 16 + lq) * 128 +
                                         (((4 * h + g) ^ (lq & 7)) * 16));
        st[t] = __builtin_amdgcn_mfma_f32_16x16x32_bf16(kf, qf[h], st[t], 0, 0, 0);
      }
    }

    // ---- online softmax (exp2 domain), per q = lane&15 ----
    float mx = st[0][0];
    #pragma unroll
    for (int t = 0; t < 4; ++t)
      #pragma unroll
      for (int r = 0; r < 4; ++r) mx = fmaxf(mx, st[t][r]);
    mx = fmaxf(mx, __shfl_xor(mx, 16));
    mx = fmaxf(mx, __shfl_xor(mx, 32));
    const float mn  = fmaxf(m, mx);
    const float fac = __builtin_amdgcn_exp2f(m - mn);
    float p[16], ps = 0.0f;
    #pragma unroll
    for (int t = 0; t < 4; ++t)
      #pragma unroll
      for (int r = 0; r < 4; ++r) {
        float e = __builtin_amdgcn_exp2f(st[t][r] - mn);
        p[t * 4 + r] = e;
        ps += e;
      }
    ps += __shfl_xor(ps, 16);
    ps += __shfl_xor(ps, 32);
    l = l * fac + ps;   // denominator excludes dropout mask (reference masks post-softmax)
    m = mn;
    #pragma unroll
    for (int dt = 0; dt < 4; ++dt)
      #pragma unroll
      for (int r = 0; r < 4; ++r) acc[dt][r] *= fac;

    // ---- mask, pack bf16, stash P (wave-private, swizzled like K/V) ----
    #pragma unroll
    for (int t = 0; t < 4; ++t) {
      s16x4 pk;
      #pragma unroll
      for (int r = 0; r < 4; ++r) pk[r] = f2bf(p[t * 4 + r] * mk[t][r]);
      *(s16x4*)(pl + (((2 * t + (g >> 1)) ^ (lq & 7)) * 16) + (g & 1) * 8) = pk;
    }
    asm volatile("" ::: "memory");

    // ---- swapped PV: acc rows = d, cols = q ----
    #pragma unroll
    for (int c = 0; c < 2; ++c) {
      const s16x8 pf = *(const s16x8*)(pl + (((4 * c + g) ^ (lq & 7)) * 16));
      #pragma unroll
      for (int dt = 0; dt < 4; ++dt) {
        const s16x8 vf = *(const s16x8*)(vl + cur * 8192 + (dt * 16 + lq) * 128 +
                                         (((4 * c + g) ^ (lq & 7)) * 16));
        acc[dt] = __builtin_amdgcn_mfma_f32_16x16x32_bf16(vf, pf, acc[dt], 0, 0, 0);
      }
    }

    __syncthreads();   // implicit vmcnt(0): next buffer's DMA has landed
    cur ^= 1;
  }

  const float inv_l = 1.0f / l;
  float* op = Og + base + (size_t)qrow * D;
  #pragma unroll
  for (int dt = 0; dt < 4; ++dt) {
    f32x4 o;
    #pragma unroll
    for (int r = 0; r < 4; ++r) o[r] = acc[dt][r] * inv_l;
    *(f32x4*)(op + dt * 16 + g * 4) = o;
  }
}

// ============ fallback (round-1 kernel) if ws too small ============
__global__ __launch_bounds__(256, 4)
void attn_fwd_fb(const float* __restrict__ Qg, const float* __restrict__ Kg,
                 const float* __restrict__ Vg, const float* __restrict__ Mg,
                 float* __restrict__ Og) {
  __shared__ alignas(16) short Kl[32][72];
  __shared__ alignas(16) short Vl[D][40];
  __shared__ alignas(16) short Pl[4][16][40];
  const int tid = threadIdx.x, wave = tid >> 6, lane = tid & 63;
  const int lq = lane & 15, g = lane >> 4;
  const int bh = blockIdx.x & (BH - 1), qt = blockIdx.x / BH;
  const size_t base = (size_t)bh * S * D;
  const int qrow = qt * QBLK + wave * 16 + lq;
  const float* mrow = Mg + ((size_t)bh * S + qrow) * S;
  s16x8 qf[2];
  {
    const float sc = 1.44269504088896340736f * 0.125f;
    const float* qp = Qg + base + (size_t)qrow * D + g * 8;
    #pragma unroll
    for (int h = 0; h < 2; ++h) {
      f32x4 a = *(const f32x4*)(qp + h * 32);
      f32x4 b = *(const f32x4*)(qp + h * 32 + 4);
      #pragma unroll
      for (int j = 0; j < 4; ++j) { qf[h][j] = f2bf(a[j] * sc); qf[h][4 + j] = f2bf(b[j] * sc); }
    }
  }
  f32x4 acc[4];
  #pragma unroll
  for (int dt = 0; dt < 4; ++dt) acc[dt] = (f32x4)0.0f;
  float m = -1e30f, l = 0.0f;
  for (int kb = 0; kb < S; kb += 32) {
    f32x4 mk[2];
    #pragma unroll
    for (int t = 0; t < 2; ++t) mk[t] = *(const f32x4*)(mrow + kb + t * 16 + g * 4);
    __syncthreads();
    {
      const int row = tid >> 3, d0 = (tid & 7) * 8;
      const float* kp = Kg + base + (size_t)(kb + row) * D + d0;
      f32x4 a = *(const f32x4*)kp, b = *(const f32x4*)(kp + 4);
      s16x8 f;
      #pragma unroll
      for (int j = 0; j < 4; ++j) { f[j] = f2bf(a[j]); f[4 + j] = f2bf(b[j]); }
      *(s16x8*)&Kl[row][d0] = f;
    }
    {
      const int d = tid & 63, kk = (tid >> 6) * 8;
      const float* vp = Vg + base + (size_t)(kb + kk) * D + d;
      s16x8 f;
      #pragma unroll
      for (int j = 0; j < 8; ++j) f[j] = f2bf(vp[(size_t)j * D]);
      *(s16x8*)&Vl[d][kk] = f;
    }
    __syncthreads();
    f32x4 st[2];
    #pragma unroll
    for (int t = 0; t < 2; ++t) {
      st[t] = (f32x4)0.0f;
      #pragma unroll
      for (int h = 0; h < 2; ++h) {
        s16x8 kf = *(const s16x8*)&Kl[t * 16 + lq][h * 32 + g * 8];
        st[t] = __builtin_amdgcn_mfma_f32_16x16x32_bf16(kf, qf[h], st[t], 0, 0, 0);
      }
    }
    float mx = st[0][0];
    #pragma unroll
    for (int t = 0; t < 2; ++t)
      #pragma unroll
      for (int r = 0; r < 4; ++r) mx = fmaxf(mx, st[t][r]);
    mx = fmaxf(mx, __shfl_xor(mx, 16));
    mx = fmaxf(mx, __shfl_xor(mx, 32));
    const float mn = fmaxf(m, mx);
    const float fac = __builtin_amdgcn_exp2f(m - mn);
    float p[8], ps = 0.0f;
    #pragma unroll
    for (int t = 0; t < 2; ++t)
      #pragma unroll
      for (int r = 0; r < 4; ++r) { float e = __builtin_amdgcn_exp2f(st[t][r] - mn); p[t * 4 + r] = e; ps += e; }
    ps += __shfl_xor(ps, 16);
    ps += __shfl_xor(ps, 32);
    l = l * fac + ps; m = mn;
    #pragma unroll
    for (int dt = 0; dt < 4; ++dt)
      #pragma unroll
      for (int r = 0; r < 4; ++r) acc[dt][r] *= fac;
    #pragma unroll
    for (int t = 0; t < 2; ++t) {
      s16x4 pk;
      #pragma unroll
      for (int r = 0; r < 4; ++r) pk[r] = f2bf(p[t * 4 + r] * mk[t][r]);
      *(s16x4*)&Pl[wave][lq][t * 16 + g * 4] = pk;
    }
    asm volatile("" ::: "memory");
    s16x8 pf = *(const s16x8*)&Pl[wave][lq][g * 8];
    #pragma unroll
    for (int dt = 0; dt < 4; ++dt) {
      s16x8 vf = *(const s16x8*)&Vl[dt * 16 + lq][g * 8];
      acc[dt] = __builtin_amdgcn_mfma_f32_16x16x32_bf16(vf, pf, acc[dt], 0, 0, 0);
    }
  }
  const float inv_l = 1.0f / l;
  float* op = Og + base + (size_t)qrow * D;
  #pragma unroll
  for (int dt = 0; dt < 4; ++dt) {
    f32x4 o;
    #pragma unroll
    for (int r = 0; r < 4; ++r) o[r] = acc[dt][r] * inv_l;
    *(f32x4*)(op + dt * 16 + g * 4) = o;
  }
}

extern "C" void kernel_launch(void* const* d_in, const int* in_sizes, int n_in,
                              void* d_out, int out_size, void* d_ws, size_t ws_size,
                              hipStream_t stream) {
  const float* Q = (const float*)d_in[0];
  const float* K = (const float*)d_in[1];
  const float* V = (const float*)d_in[2];
  const float* M = (const float*)d_in[3];
  float* O = (float*)d_out;
  const size_t need = 2ull * BH * S * D * sizeof(short);  // Kb + Vt = 16 MB
  if (ws_size >= need) {
    short* Kb = (short*)d_ws;
    short* Vt = Kb + (size_t)BH * S * D;
    prepass<<<2 * BH * NSL, 256, 0, stream>>>(K, V, Kb, Vt);
    attn_fwd2<<<(S / QBLK) * BH, 256, 0, stream>>>(Q, Kb, Vt, M, O);
  } else {
    attn_fwd_fb<<<(S / QBLK) * BH, 256, 0, stream>>>(Q, K, V, M, O);
  }
}

// Round 3
// 171.147 us; speedup vs baseline: 1.0934x; 1.0661x over previous
//
#include <hip/hip_runtime.h>
#include <hip/hip_bf16.h>

typedef __attribute__((ext_vector_type(4))) float f32x4;
typedef __attribute__((ext_vector_type(8))) short s16x8;
typedef __attribute__((ext_vector_type(4))) short s16x4;

constexpr int S    = 2048;
constexpr int D    = 64;
constexpr int BH   = 32;        // B*H
constexpr int QBLK = 64;        // q rows per block (4 waves x 16)
constexpr int KBLK = 32;        // keys per main-loop iteration
constexpr int NSL  = S / KBLK;  // 64 iterations

__device__ __forceinline__ short f2bf(float f) {
  union { float f; unsigned u; } x;
  x.f = f;
  unsigned r = x.u + 0x7fffu + ((x.u >> 16) & 1u);  // RNE
  return (short)(r >> 16);
}

typedef const __attribute__((address_space(1))) unsigned int* as1_u32p;
typedef __attribute__((address_space(3))) unsigned int* as3_u32p;

// ============ pre-pass ============
// Kb: [bh][key][pos^swz][8] bf16, pos = d-chunk ^ (key&7). Any 32-key window = 4KB contiguous.
// Vt: [bh][slice32][d][pos^swz][8] bf16, pos = key-chunk ^ ((d>>1)&3). Slice = 4KB contiguous.
__global__ __launch_bounds__(256) void prepass(const float* __restrict__ K,
                                               const float* __restrict__ V,
                                               short* __restrict__ Kb,
                                               short* __restrict__ Vt) {
  const int bid = blockIdx.x;
  const int tid = threadIdx.x;
  if (bid < BH * 32) {
    // ---- K convert: one block per (bh, 64-key slice) ----
    const int bh = bid >> 5, sl = bid & 31;
    const float* src = K + ((size_t)bh * S + (size_t)sl * 64) * D;
    short* dst = Kb + ((size_t)bh * S + (size_t)sl * 64) * D;
    #pragma unroll
    for (int c = 0; c < 2; ++c) {
      const int idx = tid * 2 + c;   // 0..511
      const int row = idx >> 3;      // key within slice
      const int ch  = idx & 7;       // d-chunk
      const float* s = src + row * D + ch * 8;
      f32x4 a = *(const f32x4*)s, b = *(const f32x4*)(s + 4);
      s16x8 o;
      #pragma unroll
      for (int j = 0; j < 4; ++j) { o[j] = f2bf(a[j]); o[4 + j] = f2bf(b[j]); }
      *(s16x8*)(dst + row * D + ((ch ^ (row & 7)) * 8)) = o;
    }
  } else {
    // ---- V transpose: one block per (bh, 32-key slice) ----
    __shared__ short tile[32][72];
    const int b2 = bid - BH * 32;
    const int bh = b2 >> 6, sl = b2 & 63;
    const float* src = V + ((size_t)bh * S + (size_t)sl * 32) * D;
    {
      const int row = tid >> 3;          // key 0..31
      const int c0  = (tid & 7) * 8;     // 8 d-cols per thread
      f32x4 a = *(const f32x4*)(src + row * D + c0);
      f32x4 b = *(const f32x4*)(src + row * D + c0 + 4);
      #pragma unroll
      for (int j = 0; j < 4; ++j) {
        tile[row][c0 + j]     = f2bf(a[j]);
        tile[row][c0 + 4 + j] = f2bf(b[j]);
      }
    }
    __syncthreads();
    short* dst = Vt + ((size_t)bh * 64 + sl) * (D * KBLK);
    const int d = tid >> 2, c = tid & 3;
    const int pos = c ^ ((d >> 1) & 3);
    s16x8 o;
    #pragma unroll
    for (int j = 0; j < 8; ++j) o[j] = tile[c * 8 + j][d];
    *(s16x8*)(dst + d * KBLK + pos * 8) = o;
  }
}

// ============ main ============
__global__ __launch_bounds__(256, 4)
void attn_fwd3(const float* __restrict__ Qg, const short* __restrict__ Kb,
               const short* __restrict__ Vt, const float* __restrict__ Mg,
               float* __restrict__ Og) {
  __shared__ alignas(16) short K_lds[2][KBLK][64];   // 8 KB
  __shared__ alignas(16) short V_lds[2][D][KBLK];    // 8 KB
  __shared__ alignas(16) float M_lds[2][QBLK][KBLK]; // 16 KB
  __shared__ alignas(16) short P_lds[4][16][KBLK];   // 4 KB

  const int tid  = threadIdx.x;
  const int wave = tid >> 6;
  const int lane = tid & 63;
  const int lq   = lane & 15;
  const int g    = lane >> 4;

  const int bh = blockIdx.x & (BH - 1);
  const int qt = blockIdx.x / BH;
  const size_t base = (size_t)bh * S * D;
  const int    qrow = qt * QBLK + wave * 16 + lq;

  // Q fragment, pre-scaled by log2(e)/8
  s16x8 qf[2];
  {
    const float sc = 1.44269504088896340736f * 0.125f;
    const float* qp = Qg + base + (size_t)qrow * D + g * 8;
    #pragma unroll
    for (int h = 0; h < 2; ++h) {
      f32x4 a = *(const f32x4*)(qp + h * 32);
      f32x4 b = *(const f32x4*)(qp + h * 32 + 4);
      #pragma unroll
      for (int j = 0; j < 4; ++j) {
        qf[h][j]     = f2bf(a[j] * sc);
        qf[h][4 + j] = f2bf(b[j] * sc);
      }
    }
  }

  f32x4 acc[4];
  #pragma unroll
  for (int dt = 0; dt < 4; ++dt) acc[dt] = (f32x4)0.0f;
  float m = -1e30f, lp = 0.0f;   // lp: lane-partial denominator

  const char* kbase = (const char*)(Kb + base);
  const char* vbase = (const char*)(Vt + (size_t)bh * 64 * (D * KBLK));
  const char* mblock = (const char*)(Mg + ((size_t)bh * S + (size_t)qt * QBLK) * S);
  char* kl = (char*)&K_lds[0][0][0];
  char* vl = (char*)&V_lds[0][0][0];
  char* ml = (char*)&M_lds[0][0][0];
  char* pl = (char*)&P_lds[wave][lq][0];

  // DMA one iteration's K/V/mask into buf. Mask source pre-swizzled so the
  // swizzled ds_read_b128 at consume time is conflict-free (linear LDS dest).
  auto stage = [&](int buf, int it) {
    __builtin_amdgcn_global_load_lds((as1_u32p)(kbase + (size_t)it * 4096 + wave * 1024 + lane * 16),
                                     (as3_u32p)(kl + buf * 4096 + wave * 1024 + lane * 16), 16, 0, 0);
    __builtin_amdgcn_global_load_lds((as1_u32p)(vbase + (size_t)it * 4096 + wave * 1024 + lane * 16),
                                     (as3_u32p)(vl + buf * 4096 + wave * 1024 + lane * 16), 16, 0, 0);
    #pragma unroll
    for (int c = 0; c < 2; ++c) {
      const int slot = wave * 2048 + c * 1024 + lane * 16;  // byte in 8KB mask tile
      const int q  = slot >> 7;          // block-local q row
      const int p  = (slot >> 4) & 7;    // 16B chunk within row
      const char* msrc = mblock + (size_t)q * (S * 4) + (size_t)it * (KBLK * 4) + ((p ^ (q & 7)) * 16);
      __builtin_amdgcn_global_load_lds((as1_u32p)msrc, (as3_u32p)(ml + buf * 8192 + slot), 16, 0, 0);
    }
  };

  stage(0, 0);
  __syncthreads();

  int cur = 0;
  for (int it = 0; it < NSL; ++it) {
    if (it + 1 < NSL) stage(cur ^ 1, it + 1);   // full-iteration prefetch lead

    // ---- swapped QK^T: rows = keys, cols = q ----
    f32x4 st[2];
    __builtin_amdgcn_s_setprio(1);
    #pragma unroll
    for (int t = 0; t < 2; ++t) {
      st[t] = (f32x4)0.0f;
      #pragma unroll
      for (int h = 0; h < 2; ++h) {
        const s16x8 kf = *(const s16x8*)(kl + cur * 4096 + (t * 16 + lq) * 128 +
                                         (((h * 4 + g) ^ (lq & 7)) * 16));
        st[t] = __builtin_amdgcn_mfma_f32_16x16x32_bf16(kf, qf[h], st[t], 0, 0, 0);
      }
    }
    __builtin_amdgcn_s_setprio(0);

    // ---- deferred-max online softmax (exp2 domain), no cross-lane in steady state ----
    const float mx = fmaxf(fmaxf(fmaxf(st[0][0], st[0][1]), fmaxf(st[0][2], st[0][3])),
                           fmaxf(fmaxf(st[1][0], st[1][1]), fmaxf(st[1][2], st[1][3])));
    if (!__all(mx <= m + 8.0f)) {       // rare: row max grew past headroom
      float rm = fmaxf(mx, __shfl_xor(mx, 16));
      rm = fmaxf(rm, __shfl_xor(rm, 32));
      const float mn  = fmaxf(m, rm);
      const float fac = __builtin_amdgcn_exp2f(m - mn);
      lp *= fac;
      #pragma unroll
      for (int dt = 0; dt < 4; ++dt)
        #pragma unroll
        for (int r = 0; r < 4; ++r) acc[dt][r] *= fac;
      m = mn;
    }
    float p[8];
    #pragma unroll
    for (int t = 0; t < 2; ++t)
      #pragma unroll
      for (int r = 0; r < 4; ++r) p[t * 4 + r] = __builtin_amdgcn_exp2f(st[t][r] - m);
    lp += ((p[0] + p[1]) + (p[2] + p[3])) + ((p[4] + p[5]) + (p[6] + p[7]));

    // ---- apply dropout mask (from LDS, DMA'd last iter), pack, stash P ----
    #pragma unroll
    for (int t = 0; t < 2; ++t) {
      const f32x4 mk = *(const f32x4*)(ml + cur * 8192 + (wave * 16 + lq) * 128 +
                                       (((t * 4 + g) ^ (lq & 7)) * 16));
      s16x4 pk;
      #pragma unroll
      for (int r = 0; r < 4; ++r) pk[r] = f2bf(p[t * 4 + r] * mk[r]);
      *(s16x4*)(pl + (((2 * t + (g >> 1)) ^ ((lq >> 1) & 3)) * 16) + (g & 1) * 8) = pk;
    }
    asm volatile("" ::: "memory");

    // ---- swapped PV: rows = d, cols = q ----
    const s16x8 pf = *(const s16x8*)(pl + ((g ^ ((lq >> 1) & 3)) * 16));
    __builtin_amdgcn_s_setprio(1);
    #pragma unroll
    for (int dt = 0; dt < 4; ++dt) {
      const s16x8 vf = *(const s16x8*)(vl + cur * 4096 + (dt * 16 + lq) * 64 +
                                       ((g ^ ((lq >> 1) & 3)) * 16));
      acc[dt] = __builtin_amdgcn_mfma_f32_16x16x32_bf16(vf, pf, acc[dt], 0, 0, 0);
    }
    __builtin_amdgcn_s_setprio(0);

    __syncthreads();   // drains this iter's prefetch DMA (issued a full body ago)
    cur ^= 1;
  }

  // epilogue: reduce lane-partial denominator across the 4 g-groups
  float l = lp + __shfl_xor(lp, 16);
  l += __shfl_xor(l, 32);
  const float inv_l = 1.0f / l;
  float* op = Og + base + (size_t)qrow * D;
  #pragma unroll
  for (int dt = 0; dt < 4; ++dt) {
    f32x4 o;
    #pragma unroll
    for (int r = 0; r < 4; ++r) o[r] = acc[dt][r] * inv_l;
    *(f32x4*)(op + dt * 16 + g * 4) = o;
  }
}

// ============ fallback (round-1 kernel) if ws too small ============
__global__ __launch_bounds__(256, 4)
void attn_fwd_fb(const float* __restrict__ Qg, const float* __restrict__ Kg,
                 const float* __restrict__ Vg, const float* __restrict__ Mg,
                 float* __restrict__ Og) {
  __shared__ alignas(16) short Kl[32][72];
  __shared__ alignas(16) short Vl[D][40];
  __shared__ alignas(16) short Pl[4][16][40];
  const int tid = threadIdx.x, wave = tid >> 6, lane = tid & 63;
  const int lq = lane & 15, g = lane >> 4;
  const int bh = blockIdx.x & (BH - 1), qt = blockIdx.x / BH;
  const size_t base = (size_t)bh * S * D;
  const int qrow = qt * QBLK + wave * 16 + lq;
  const float* mrow = Mg + ((size_t)bh * S + qrow) * S;
  s16x8 qf[2];
  {
    const float sc = 1.44269504088896340736f * 0.125f;
    const float* qp = Qg + base + (size_t)qrow * D + g * 8;
    #pragma unroll
    for (int h = 0; h < 2; ++h) {
      f32x4 a = *(const f32x4*)(qp + h * 32);
      f32x4 b = *(const f32x4*)(qp + h * 32 + 4);
      #pragma unroll
      for (int j = 0; j < 4; ++j) { qf[h][j] = f2bf(a[j] * sc); qf[h][4 + j] = f2bf(b[j] * sc); }
    }
  }
  f32x4 acc[4];
  #pragma unroll
  for (int dt = 0; dt < 4; ++dt) acc[dt] = (f32x4)0.0f;
  float m = -1e30f, l = 0.0f;
  for (int kb = 0; kb < S; kb += 32) {
    f32x4 mk[2];
    #pragma unroll
    for (int t = 0; t < 2; ++t) mk[t] = *(const f32x4*)(mrow + kb + t * 16 + g * 4);
    __syncthreads();
    {
      const int row = tid >> 3, d0 = (tid & 7) * 8;
      const float* kp = Kg + base + (size_t)(kb + row) * D + d0;
      f32x4 a = *(const f32x4*)kp, b = *(const f32x4*)(kp + 4);
      s16x8 f;
      #pragma unroll
      for (int j = 0; j < 4; ++j) { f[j] = f2bf(a[j]); f[4 + j] = f2bf(b[j]); }
      *(s16x8*)&Kl[row][d0] = f;
    }
    {
      const int d = tid & 63, kk = (tid >> 6) * 8;
      const float* vp = Vg + base + (size_t)(kb + kk) * D + d;
      s16x8 f;
      #pragma unroll
      for (int j = 0; j < 8; ++j) f[j] = f2bf(vp[(size_t)j * D]);
      *(s16x8*)&Vl[d][kk] = f;
    }
    __syncthreads();
    f32x4 st[2];
    #pragma unroll
    for (int t = 0; t < 2; ++t) {
      st[t] = (f32x4)0.0f;
      #pragma unroll
      for (int h = 0; h < 2; ++h) {
        s16x8 kf = *(const s16x8*)&Kl[t * 16 + lq][h * 32 + g * 8];
        st[t] = __builtin_amdgcn_mfma_f32_16x16x32_bf16(kf, qf[h], st[t], 0, 0, 0);
      }
    }
    float mx = st[0][0];
    #pragma unroll
    for (int t = 0; t < 2; ++t)
      #pragma unroll
      for (int r = 0; r < 4; ++r) mx = fmaxf(mx, st[t][r]);
    mx = fmaxf(mx, __shfl_xor(mx, 16));
    mx = fmaxf(mx, __shfl_xor(mx, 32));
    const float mn = fmaxf(m, mx);
    const float fac = __builtin_amdgcn_exp2f(m - mn);
    float p[8], ps = 0.0f;
    #pragma unroll
    for (int t = 0; t < 2; ++t)
      #pragma unroll
      for (int r = 0; r < 4; ++r) { float e = __builtin_amdgcn_exp2f(st[t][r] - mn); p[t * 4 + r] = e; ps += e; }
    ps += __shfl_xor(ps, 16);
    ps += __shfl_xor(ps, 32);
    l = l * fac + ps; m = mn;
    #pragma unroll
    for (int dt = 0; dt < 4; ++dt)
      #pragma unroll
      for (int r = 0; r < 4; ++r) acc[dt][r] *= fac;
    #pragma unroll
    for (int t = 0; t < 2; ++t) {
      s16x4 pk;
      #pragma unroll
      for (int r = 0; r < 4; ++r) pk[r] = f2bf(p[t * 4 + r] * mk[t][r]);
      *(s16x4*)&Pl[wave][lq][t * 16 + g * 4] = pk;
    }
    asm volatile("" ::: "memory");
    s16x8 pf = *(const s16x8*)&Pl[wave][lq][g * 8];
    #pragma unroll
    for (int dt = 0; dt < 4; ++dt) {
      s16x8 vf = *(const s16x8*)&Vl[dt * 16 + lq][g * 8];
      acc[dt] = __builtin_amdgcn_mfma_f32_16x16x32_bf16(vf, pf, acc[dt], 0, 0, 0);
    }
  }
  const float inv_l = 1.0f / l;
  float* op = Og + base + (size_t)qrow * D;
  #pragma unroll
  for (int dt = 0; dt < 4; ++dt) {
    f32x4 o;
    #pragma unroll
    for (int r = 0; r < 4; ++r) o[r] = acc[dt][r] * inv_l;
    *(f32x4*)(op + dt * 16 + g * 4) = o;
  }
}

extern "C" void kernel_launch(void* const* d_in, const int* in_sizes, int n_in,
                              void* d_out, int out_size, void* d_ws, size_t ws_size,
                              hipStream_t stream) {
  const float* Q = (const float*)d_in[0];
  const float* K = (const float*)d_in[1];
  const float* V = (const float*)d_in[2];
  const float* M = (const float*)d_in[3];
  float* O = (float*)d_out;
  const size_t need = 2ull * BH * S * D * sizeof(short);  // Kb + Vt = 16 MB
  if (ws_size >= need) {
    short* Kb = (short*)d_ws;
    short* Vt = Kb + (size_t)BH * S * D;
    prepass<<<BH * 32 + BH * 64, 256, 0, stream>>>(K, V, Kb, Vt);
    attn_fwd3<<<(S / QBLK) * BH, 256, 0, stream>>>(Q, Kb, Vt, M, O);
  } else {
    attn_fwd_fb<<<(S / QBLK) * BH, 256, 0, stream>>>(Q, K, V, M, O);
  }
}